// Round 4
// baseline (609.353 us; speedup 1.0000x reference)
//
#include <hip/hip_runtime.h>
#include <hip/hip_bf16.h>

#define DEVFN __device__ __forceinline__

constexpr int Bb = 4, Nn = 2048, Dd = 512, Hh = 8, DVv = 64, DOo = 512;

typedef short short8 __attribute__((ext_vector_type(8)));
typedef float f32x4 __attribute__((ext_vector_type(4)));

typedef __attribute__((address_space(1))) void GV;   // global
typedef __attribute__((address_space(3))) void LV;   // LDS

DEVFN unsigned short f32_bf16(float f) {
  unsigned u = __builtin_bit_cast(unsigned, f);
  u += 0x7fffu + ((u >> 16) & 1u);          // RNE
  return (unsigned short)(u >> 16);
}

DEVFN void barrier_raw() {
  asm volatile("" ::: "memory");
  __builtin_amdgcn_s_barrier();
  asm volatile("" ::: "memory");
}

template<int Nv> DEVFN void wait_vmcnt() {
  if constexpr (Nv == 0)      asm volatile("s_waitcnt vmcnt(0)"  ::: "memory");
  else if constexpr (Nv == 4) asm volatile("s_waitcnt vmcnt(4)"  ::: "memory");
  else if constexpr (Nv == 6) asm volatile("s_waitcnt vmcnt(6)"  ::: "memory");
  else if constexpr (Nv == 8) asm volatile("s_waitcnt vmcnt(8)"  ::: "memory");
  else static_assert(Nv == 0 || Nv == 4 || Nv == 6 || Nv == 8, "bad vmcnt");
}
DEVFN void wait_lgkm0() { asm volatile("s_waitcnt lgkmcnt(0)" ::: "memory"); }

// Stage TOTAL bytes into LDS with NTHR threads. Linear LDS dest (required by
// global_load_lds), XOR-swizzled GLOBAL source so that a swizzled ds_read is
// conflict-free: LDS(row,blk) holds global(row, blk ^ (row & mask)).
template<int ROWBYTES, int TOTAL, int NTHR = 256>
DEVFN void stage_tile(const char* g, int strideBytes, char* lds, int tid) {
  constexpr int MASK = (ROWBYTES >> 4) - 1;
#pragma unroll
  for (int off = 0; off < TOTAL; off += NTHR * 16) {
    int o   = off + tid * 16;
    int row = o / ROWBYTES;
    int blk = (o >> 4) & MASK;
    int sb  = blk ^ (row & MASK & 7);   // cap swizzle span at 8 (128B rows)
    const char* src = g + (size_t)row * strideBytes + (sb << 4);
    __builtin_amdgcn_global_load_lds((GV*)src, (LV*)(lds + o), 16, 0, 0);
  }
}

template<int ROWBYTES>
DEVFN short8 frag_ld(const char* lds, int row, int kbyte) {
  constexpr int MASK = (ROWBYTES >> 4) - 1;
  int blk = kbyte >> 4;
  int sb  = blk ^ (row & MASK & 7);
  return *(const short8*)(lds + row * ROWBYTES + (sb << 4));
}

DEVFN f32x4 mfma16(short8 a, short8 b, f32x4 c) {
  return __builtin_amdgcn_mfma_f32_16x16x32_bf16(a, b, c, 0, 0, 0);
}

// ---------------- small prep kernels ----------------

__global__ void cvt_f32_bf16_kernel(const float* __restrict__ in,
                                    unsigned short* __restrict__ out, int n4) {
  int i = blockIdx.x * blockDim.x + threadIdx.x;
  if (i < n4) {
    float4 v = ((const float4*)in)[i];
    ushort4 o;
    o.x = f32_bf16(v.x); o.y = f32_bf16(v.y);
    o.z = f32_bf16(v.z); o.w = f32_bf16(v.w);
    ((ushort4*)out)[i] = o;
  }
}

// mask int32 {0,1} -> bf16 keep {1.0, 0.0}
__global__ void mask_prep_kernel(const int* __restrict__ m,
                                 unsigned short* __restrict__ ms, int n4) {
  int i = blockIdx.x * blockDim.x + threadIdx.x;
  if (i < n4) {
    int4 v = ((const int4*)m)[i];
    ushort4 o;
    o.x = v.x ? 0 : 0x3f80; o.y = v.y ? 0 : 0x3f80;
    o.z = v.z ? 0 : 0x3f80; o.w = v.w ? 0 : 0x3f80;
    ((ushort4*)ms)[i] = o;
  }
}

// in: [G][R][C] f32 -> out: [G][C][R] bf16
__global__ void transpose_w_kernel(const float* __restrict__ in,
                                   unsigned short* __restrict__ out, int R, int C) {
  __shared__ float t[32][33];
  int g = blockIdx.z;
  int c0 = blockIdx.x * 32, r0 = blockIdx.y * 32;
  const float* ip = in + (size_t)g * R * C;
  unsigned short* op = out + (size_t)g * R * C;
#pragma unroll
  for (int i = threadIdx.y; i < 32; i += 8)
    t[i][threadIdx.x] = ip[(size_t)(r0 + i) * C + c0 + threadIdx.x];
  __syncthreads();
#pragma unroll
  for (int i = threadIdx.y; i < 32; i += 8)
    op[(size_t)(c0 + i) * R + r0 + threadIdx.x] = f32_bf16(t[threadIdx.x][i]);
}

// in: [G][R][C] bf16 -> out: [G][C][R] bf16
__global__ void transpose_u16_kernel(const unsigned short* __restrict__ in,
                                     unsigned short* __restrict__ out, int R, int C) {
  __shared__ unsigned short t[32][33];
  int g = blockIdx.z;
  int c0 = blockIdx.x * 32, r0 = blockIdx.y * 32;
  const unsigned short* ip = in + (size_t)g * R * C;
  unsigned short* op = out + (size_t)g * R * C;
#pragma unroll
  for (int i = threadIdx.y; i < 32; i += 8)
    t[i][threadIdx.x] = ip[(size_t)(r0 + i) * C + c0 + threadIdx.x];
  __syncthreads();
#pragma unroll
  for (int i = threadIdx.y; i < 32; i += 8)
    op[(size_t)(c0 + i) * R + r0 + threadIdx.x] = t[threadIdx.x][i];
}

// ---------------- 256x256-tile NT GEMM, K=512, counted-vmcnt ring ----------------
// C[M x NTN*256] = A[M x 512] * Bt[... x 512]^T per group g.
// 512 thr / 8 waves (2M x 4N); wave output 128x64. BK_sub=32, 4-slot LDS ring
// per operand (4x16KB x 2 = 128KB). 16 phases: {vmcnt(8); barrier; 12 ds_read;
// stage sub u+3; setprio(1); 32 MFMA; setprio(0); barrier}. Prefetch dist 3.
// EPI 0: bf16 out, head-strided rows (proj). EPI 1: f32 attn out, mask*scale.

template<int NTM, int NTN, int NG, int EPI>
__global__ __launch_bounds__(512, 2)
void gemm256_kernel(const char* __restrict__ A, long sAg,
                    const char* __restrict__ Bt, long sBg,
                    void* __restrict__ C, const unsigned short* __restrict__ ms) {
  __shared__ alignas(16) char Asl[4][16384];
  __shared__ alignas(16) char Bsl[4][16384];
  int tid = threadIdx.x, lane = tid & 63;
  int w = tid >> 6, wr = w >> 2, wc = w & 3;

  constexpr int TOT = NTM * NTN * NG;
  int fid = blockIdx.x;
  int swz = (fid & 7) * (TOT / 8) + (fid >> 3);   // TOT % 8 == 0
  int g = swz / (NTM * NTN), rem = swz % (NTM * NTN);
  int tM = rem % NTM, tN = rem / NTM;

  const char* Ag = A + (size_t)g * sAg + (size_t)tM * 256 * 1024;
  const char* Bg = Bt + (size_t)g * sBg + (size_t)tN * 256 * 1024;

  f32x4 acc[8][4] = {};

  // prologue: subs 0,1,2 -> slots 0,1,2
#pragma unroll
  for (int u = 0; u < 3; ++u) {
    stage_tile<64, 16384, 512>(Ag + u * 64, 1024, Asl[u], tid);
    stage_tile<64, 16384, 512>(Bg + u * 64, 1024, Bsl[u], tid);
  }

#pragma unroll
  for (int u = 0; u < 16; ++u) {
    if (u <= 13)      wait_vmcnt<8>();
    else if (u == 14) wait_vmcnt<4>();
    else              wait_vmcnt<0>();
    barrier_raw();
    short8 af[8], bfr[4];
#pragma unroll
    for (int rg = 0; rg < 8; ++rg)
      af[rg] = frag_ld<64>(Asl[u & 3], wr * 128 + rg * 16 + (lane & 15),
                           (lane >> 4) * 16);
#pragma unroll
    for (int cg = 0; cg < 4; ++cg)
      bfr[cg] = frag_ld<64>(Bsl[u & 3], wc * 64 + cg * 16 + (lane & 15),
                            (lane >> 4) * 16);
    if (u < 13) {
      stage_tile<64, 16384, 512>(Ag + (u + 3) * 64, 1024, Asl[(u + 3) & 3], tid);
      stage_tile<64, 16384, 512>(Bg + (u + 3) * 64, 1024, Bsl[(u + 3) & 3], tid);
    }
    __builtin_amdgcn_s_setprio(1);
#pragma unroll
    for (int rg = 0; rg < 8; ++rg)
#pragma unroll
      for (int cg = 0; cg < 4; ++cg)
        acc[rg][cg] = mfma16(af[rg], bfr[cg], acc[rg][cg]);
    __builtin_amdgcn_s_setprio(0);
    barrier_raw();
  }

  const float scale = 0.044194173824159216f;   // 1/sqrt(512)
#pragma unroll
  for (int rg = 0; rg < 8; ++rg)
#pragma unroll
    for (int cg = 0; cg < 4; ++cg)
#pragma unroll
      for (int r = 0; r < 4; ++r) {
        int rowL = wr * 128 + rg * 16 + (lane >> 4) * 4 + r;
        int colL = wc * 64 + cg * 16 + (lane & 15);
        int grow = tM * 256 + rowL;
        int col  = tN * 256 + colL;
        if constexpr (EPI == 0) {
          size_t orow = ((size_t)(grow >> 11) * Hh + g) * 2048 + (grow & 2047);
          ((unsigned short*)C)[orow * 512 + col] = f32_bf16(acc[rg][cg][r]);
        } else {
          unsigned short kv = ms[(size_t)grow * Nn + col];
          float keep = __builtin_bit_cast(float, (unsigned)kv << 16);
          ((float*)C)[((size_t)g * Nn + grow) * Nn + col] =
              acc[rg][cg][r] * scale * keep;
        }
      }
}

// ---------------- NT GEMM 128-tile (kept for V-proj and Wo) ----------------

template<int NCG, bool OUTF32>
__global__ __launch_bounds__(256)
void gemm_nt_kernel(const unsigned short* __restrict__ A,
                    const unsigned short* __restrict__ BtAll,
                    void* __restrict__ Cb, int HeadsOut, int Ncols) {
  constexpr int BN = NCG * 32;
  constexpr int NL = 4 + BN / 32;
  __shared__ alignas(16) char As[2][16384];
  __shared__ alignas(16) char Bs[2][BN * 128];
  int tid = threadIdx.x, lane = tid & 63;
  int w = tid >> 6, wr = w >> 1, wc = w & 1;
  int tM = blockIdx.x, tN = blockIdx.y, h = blockIdx.z;
  const char* Ab  = (const char*)A + ((size_t)tM * 128) * 1024;
  const char* Btb = (const char*)BtAll + ((size_t)h * Ncols + tN * BN) * 1024;

  f32x4 acc[4][NCG] = {};

  stage_tile<128, 16384>(Ab, 1024, As[0], tid);
  stage_tile<128, BN * 128>(Btb, 1024, Bs[0], tid);
#pragma unroll
  for (int kk = 0; kk < 8; ++kk) {
    int cur = kk & 1;
    if (kk < 7) {
      stage_tile<128, 16384>(Ab + (kk + 1) * 128, 1024, As[cur ^ 1], tid);
      stage_tile<128, BN * 128>(Btb + (kk + 1) * 128, 1024, Bs[cur ^ 1], tid);
      wait_vmcnt<NL == 8 ? 8 : 6>();
    } else {
      wait_vmcnt<0>();
    }
    barrier_raw();
#pragma unroll
    for (int c = 0; c < 2; ++c) {
      short8 af[4], bf[NCG];
#pragma unroll
      for (int rg = 0; rg < 4; ++rg)
        af[rg] = frag_ld<128>(As[cur], wr * 64 + rg * 16 + (lane & 15),
                              c * 64 + (lane >> 4) * 16);
#pragma unroll
      for (int cg = 0; cg < NCG; ++cg)
        bf[cg] = frag_ld<128>(Bs[cur], wc * (NCG * 16) + cg * 16 + (lane & 15),
                              c * 64 + (lane >> 4) * 16);
#pragma unroll
      for (int rg = 0; rg < 4; ++rg)
#pragma unroll
        for (int cg = 0; cg < NCG; ++cg)
          acc[rg][cg] = mfma16(af[rg], bf[cg], acc[rg][cg]);
    }
    barrier_raw();
  }

#pragma unroll
  for (int rg = 0; rg < 4; ++rg)
#pragma unroll
    for (int cg = 0; cg < NCG; ++cg)
#pragma unroll
      for (int r = 0; r < 4; ++r) {
        int grow = tM * 128 + wr * 64 + rg * 16 + (lane >> 4) * 4 + r;
        int col  = tN * BN + wc * (NCG * 16) + cg * 16 + (lane & 15);
        size_t orow = ((size_t)(grow >> 11) * HeadsOut + h) * 2048 + (grow & 2047);
        if constexpr (OUTF32)
          ((float*)Cb)[orow * Ncols + col] = acc[rg][cg][r];
        else
          ((unsigned short*)Cb)[orow * Ncols + col] = f32_bf16(acc[rg][cg][r]);
      }
}

// ---------------- O = S * V  (S f32 from d_out, V^T bf16) ----------------

__global__ __launch_bounds__(256)
void pv_kernel(const float* __restrict__ attn,
               const unsigned short* __restrict__ VbT,
               unsigned short* __restrict__ QKV) {
  __shared__ alignas(16) char As[2][8192];    // 64 x 64 bf16 (swizzled)
  __shared__ alignas(16) char Bs[2][8192];    // 64 x 64 bf16 (swizzled)
  int tid = threadIdx.x, lane = tid & 63;
  int w = tid >> 6, wr = w >> 1, wc = w & 1;
  int tM = blockIdx.x, bh = blockIdx.y;
  int b = bh >> 3, h = bh & 7;

  int arow = tid >> 2, aseg = tid & 3;        // 64 rows x 4 segs of 16 floats
  const float* Ag = attn + ((size_t)bh * Nn + (size_t)tM * 64 + arow) * Nn
                    + aseg * 16;
  const char* Btb = (const char*)VbT + (size_t)bh * DVv * Nn * 2;

  f32x4 acc[2][2] = {};

  auto packA = [&](float4 ar[4], char* dst) {
    short8 s0, s1;
#pragma unroll
    for (int e = 0; e < 4; ++e) {
      s0[e]     = (short)f32_bf16(ar[0][e]);
      s0[e + 4] = (short)f32_bf16(ar[1][e]);
      s1[e]     = (short)f32_bf16(ar[2][e]);
      s1[e + 4] = (short)f32_bf16(ar[3][e]);
    }
    int b0 = (aseg * 2) ^ (arow & 7), b1 = (aseg * 2 + 1) ^ (arow & 7);
    *(short8*)(dst + arow * 128 + (b0 << 4)) = s0;
    *(short8*)(dst + arow * 128 + (b1 << 4)) = s1;
  };

  {
    float4 ar[4];
#pragma unroll
    for (int i = 0; i < 4; ++i) ar[i] = ((const float4*)Ag)[i];
    stage_tile<128, 8192>(Btb, Nn * 2, Bs[0], tid);
    wait_vmcnt<0>();
    packA(ar, As[0]);
    wait_lgkm0();
    barrier_raw();
  }

#pragma unroll 2
  for (int kk = 0; kk < 32; ++kk) {
    int cur = kk & 1;
    float4 ar[4];
    if (kk < 31) {
      const float* an = Ag + (kk + 1) * 64;
#pragma unroll
      for (int i = 0; i < 4; ++i) ar[i] = ((const float4*)an)[i];
      stage_tile<128, 8192>(Btb + (kk + 1) * 128, Nn * 2, Bs[cur ^ 1], tid);
    }
#pragma unroll
    for (int c = 0; c < 2; ++c) {
      short8 af[2], bf2[2];
#pragma unroll
      for (int rg = 0; rg < 2; ++rg)
        af[rg] = frag_ld<128>(As[cur], wr * 32 + rg * 16 + (lane & 15),
                              c * 64 + (lane >> 4) * 16);
#pragma unroll
      for (int cg = 0; cg < 2; ++cg)
        bf2[cg] = frag_ld<128>(Bs[cur], wc * 32 + cg * 16 + (lane & 15),
                               c * 64 + (lane >> 4) * 16);
#pragma unroll
      for (int rg = 0; rg < 2; ++rg)
#pragma unroll
        for (int cg = 0; cg < 2; ++cg)
          acc[rg][cg] = mfma16(af[rg], bf2[cg], acc[rg][cg]);
    }
    if (kk < 31) {
      wait_vmcnt<0>();
      packA(ar, As[cur ^ 1]);
      wait_lgkm0();
    }
    barrier_raw();
  }

#pragma unroll
  for (int rg = 0; rg < 2; ++rg)
#pragma unroll
    for (int cg = 0; cg < 2; ++cg)
#pragma unroll
      for (int r = 0; r < 4; ++r) {
        int rowL = wr * 32 + rg * 16 + (lane >> 4) * 4 + r;
        int colL = wc * 32 + cg * 16 + (lane & 15);
        size_t grow = (size_t)tM * 64 + rowL;
        QKV[((size_t)b * Nn + grow) * (Hh * DVv) + h * DVv + colL] =
            f32_bf16(acc[rg][cg][r]);
      }
}

// ---------------- host ----------------

extern "C" void kernel_launch(void* const* d_in, const int* in_sizes, int n_in,
                              void* d_out, int out_size, void* d_ws, size_t ws_size,
                              hipStream_t stream) {
  const float* q    = (const float*)d_in[0];
  const float* k    = (const float*)d_in[1];
  const float* v    = (const float*)d_in[2];
  const int*   mask = (const int*)d_in[3];
  const float* Wq   = (const float*)d_in[4];
  const float* Wk   = (const float*)d_in[5];
  const float* Wv   = (const float*)d_in[6];
  const float* Wo   = (const float*)d_in[7];

  char* ws = (char*)d_ws;
  size_t off = 0;
  auto alloc = [&](size_t bytes) {
    char* p = ws + off;
    off += (bytes + 255) & ~(size_t)255;
    return p;
  };
  unsigned short* WqT  = (unsigned short*)alloc((size_t)Hh * Dd * Dd * 2);
  unsigned short* WkT  = (unsigned short*)alloc((size_t)Hh * Dd * Dd * 2);
  unsigned short* WvT  = (unsigned short*)alloc((size_t)Hh * DVv * Dd * 2);
  unsigned short* WoT  = (unsigned short*)alloc((size_t)DOo * Hh * DVv * 2);
  unsigned short* Xq   = (unsigned short*)alloc((size_t)Bb * Nn * Dd * 2);
  unsigned short* Xk   = (unsigned short*)alloc((size_t)Bb * Nn * Dd * 2);
  unsigned short* Xv   = (unsigned short*)alloc((size_t)Bb * Nn * Dd * 2);
  unsigned short* Qb   = (unsigned short*)alloc((size_t)Bb * Hh * Nn * Dd * 2);
  unsigned short* Kb   = (unsigned short*)alloc((size_t)Bb * Hh * Nn * Dd * 2);
  unsigned short* Vb   = (unsigned short*)alloc((size_t)Bb * Hh * Nn * DVv * 2);
  unsigned short* VbT  = (unsigned short*)alloc((size_t)Bb * Hh * DVv * Nn * 2);
  unsigned short* QKVb = (unsigned short*)alloc((size_t)Bb * Nn * Hh * DVv * 2);
  unsigned short* Ms   = (unsigned short*)alloc((size_t)Nn * Nn * 2);

  int n4 = Bb * Nn * Dd / 4;
  cvt_f32_bf16_kernel<<<dim3(n4 / 256), dim3(256), 0, stream>>>(q, Xq, n4);
  cvt_f32_bf16_kernel<<<dim3(n4 / 256), dim3(256), 0, stream>>>(k, Xk, n4);
  cvt_f32_bf16_kernel<<<dim3(n4 / 256), dim3(256), 0, stream>>>(v, Xv, n4);
  mask_prep_kernel<<<dim3(Nn * Nn / 4 / 256), dim3(256), 0, stream>>>(mask, Ms, Nn * Nn / 4);

  transpose_w_kernel<<<dim3(Dd / 32, Dd / 32, Hh), dim3(32, 8), 0, stream>>>(Wq, WqT, Dd, Dd);
  transpose_w_kernel<<<dim3(Dd / 32, Dd / 32, Hh), dim3(32, 8), 0, stream>>>(Wk, WkT, Dd, Dd);
  transpose_w_kernel<<<dim3(DVv / 32, Dd / 32, Hh), dim3(32, 8), 0, stream>>>(Wv, WvT, Dd, DVv);
  transpose_w_kernel<<<dim3(DOo / 32, (Hh * DVv) / 32, 1), dim3(32, 8), 0, stream>>>(Wo, WoT, Hh * DVv, DOo);

  // Q/K projections: 256^2 ring template, grid 512 (32x2 tiles x 8 heads)
  gemm256_kernel<32, 2, 8, 0><<<dim3(512), dim3(512), 0, stream>>>(
      (const char*)Xq, 0L, (const char*)WqT, (long)Dd * Dd * 2, Qb, nullptr);
  gemm256_kernel<32, 2, 8, 0><<<dim3(512), dim3(512), 0, stream>>>(
      (const char*)Xk, 0L, (const char*)WkT, (long)Dd * Dd * 2, Kb, nullptr);
  gemm_nt_kernel<2, false><<<dim3(64, 1, Hh), dim3(256), 0, stream>>>(Xv, WvT, Vb, Hh, DVv);

  transpose_u16_kernel<<<dim3(DVv / 32, Nn / 32, Bb * Hh), dim3(32, 8), 0, stream>>>(Vb, VbT, Nn, DVv);

  float* outp  = (float*)d_out;
  float* attnp = outp + (size_t)Bb * Nn * DOo;

  // qk: 256^2 ring template, grid 2048 (8x8 tiles x 32 bh)
  gemm256_kernel<8, 8, 32, 1><<<dim3(2048), dim3(512), 0, stream>>>(
      (const char*)Qb, (long)Nn * Dd * 2, (const char*)Kb, (long)Nn * Dd * 2,
      attnp, Ms);

  pv_kernel<<<dim3(32, 32), dim3(256), 0, stream>>>(attnp, VbT, QKVb);

  gemm_nt_kernel<4, true><<<dim3(64, 4, 1), dim3(256), 0, stream>>>(QKVb, WoT, outp, 1, DOo);

  (void)in_sizes; (void)n_in; (void)out_size; (void)ws_size;
}